// Round 1
// baseline (924.015 us; speedup 1.0000x reference)
//
#include <hip/hip_runtime.h>

#define CAR 8
#define NAG 64
#define SROW 520   // CAR + 64*CAR
#define HID 256
#define EOUT 257
#define QIN 265
#define ADIM 30
#define NB 4       // batch elems per K2 block

// ---------------------------------------------------------------------------
// K1: encoder + masked sum-pool.
// grid (B, 5), block 64 (one wave). blockIdx.y = eg: e-groups of 64 columns
// (eg 0..3 -> e = eg*64 + [0,64); eg 4 -> the single column e=256).
// Thread = agent n. All weight addresses are wave-uniform -> SMEM (s_load)
// path; h and acc stay in VGPRs; no LDS at all.
// ---------------------------------------------------------------------------
__global__ __launch_bounds__(64)
void k1_encoder(const float* __restrict__ s, const float* __restrict__ W1,
                const float* __restrict__ b1, const float* __restrict__ W2,
                const float* __restrict__ b2, float* __restrict__ so) {
  const int b  = blockIdx.x;
  const int eg = blockIdx.y;
  const int n  = threadIdx.x;

  // surr[n][0..7]; byte offset = 4*(520*b + 8 + 8*n), 16B aligned.
  const float* srow = s + (size_t)b * SROW + CAR + n * CAR;
  const float4 sa = ((const float4*)srow)[0];
  const float4 sb = ((const float4*)srow)[1];
  float sur[8] = {sa.x, sa.y, sa.z, sa.w, sb.x, sb.y, sb.z, sb.w};
  bool inval = false;
#pragma unroll
  for (int c = 0; c < 8; ++c) inval |= (sur[c] == -1.0f);
  const float validf = inval ? 0.0f : 1.0f;

  if (eg < 4) {
    const int ebase = eg * 64;
    float acc[64];
#pragma unroll
    for (int e = 0; e < 64; ++e) acc[e] = 0.0f;

    for (int kt = 0; kt < 16; ++kt) {      // K=256 in tiles of 16
      const int k0 = kt * 16;
      float h[16];
#pragma unroll
      for (int kk = 0; kk < 16; ++kk) {    // h = relu(surr @ W1 + b1)
        float hv = b1[k0 + kk];
#pragma unroll
        for (int c = 0; c < 8; ++c)
          hv = fmaf(sur[c], W1[c * HID + k0 + kk], hv);
        h[kk] = fmaxf(hv, 0.0f);
      }
#pragma unroll
      for (int kk = 0; kk < 16; ++kk) {    // acc[e] += h[k] * W2[k][e]
        const float* w2r = W2 + (size_t)(k0 + kk) * EOUT + ebase;
#pragma unroll
        for (int e = 0; e < 64; ++e)
          acc[e] = fmaf(h[kk], w2r[e], acc[e]);
      }
    }
    // enc = relu(acc + b2) * valid  (per agent n, per column e)
#pragma unroll
    for (int e = 0; e < 64; ++e)
      acc[e] = fmaxf(acc[e] + b2[ebase + e], 0.0f) * validf;

    // Cross-lane transpose-reduce: lane n ends with sum over agents of
    // column e = n. 63 shuffles total, no LDS.
#pragma unroll
    for (int st = 0; st < 6; ++st) {
      const int m    = 1 << st;
      const int half = 32 >> st;           // new length after this step
      const bool hi  = (n & m) != 0;
#pragma unroll
      for (int j = 0; j < half; ++j) {
        const float keep = hi ? acc[2 * j + 1] : acc[2 * j];
        const float send = hi ? acc[2 * j]     : acc[2 * j + 1];
        const float recv = __shfl_xor(send, m, 64);
        acc[j] = keep + recv;
      }
    }
    so[(size_t)b * EOUT + ebase + n] = acc[0];
  } else {
    // single column e = 256
    float acc0 = 0.0f;
    for (int kt = 0; kt < 16; ++kt) {
      const int k0 = kt * 16;
#pragma unroll
      for (int kk = 0; kk < 16; ++kk) {
        float hv = b1[k0 + kk];
#pragma unroll
        for (int c = 0; c < 8; ++c)
          hv = fmaf(sur[c], W1[c * HID + k0 + kk], hv);
        hv = fmaxf(hv, 0.0f);
        acc0 = fmaf(hv, W2[(size_t)(k0 + kk) * EOUT + 256], acc0);
      }
    }
    acc0 = fmaxf(acc0 + b2[256], 0.0f) * validf;
#pragma unroll
    for (int m = 1; m < 64; m <<= 1)
      acc0 += __shfl_xor(acc0, m, 64);
    if (n == 0) so[(size_t)b * EOUT + 256] = acc0;
  }
}

// ---------------------------------------------------------------------------
// K2: Q-head. q = relu(x @ Qw1 + Qb1) @ Qw2 + Qb2, x = [self(8), sumout(257)].
// Block = 256 threads, NB=4 batch elems per block (amortizes Qw1 traffic 4x).
// Thread t owns hidden unit t; x elements are wave-uniform scalar loads.
// ---------------------------------------------------------------------------
__global__ __launch_bounds__(256)
void k2_qhead(const float* __restrict__ s, const float* __restrict__ so,
              const float* __restrict__ Qw1, const float* __restrict__ Qb1,
              const float* __restrict__ Qw2, const float* __restrict__ Qb2,
              float* __restrict__ out, int B) {
  const int t  = threadIdx.x;
  const int b0 = blockIdx.x * NB;
  __shared__ float hq[NB][HID];

  float a[NB];
  const float qb = Qb1[t];
#pragma unroll
  for (int i = 0; i < NB; ++i) a[i] = qb;

#pragma unroll
  for (int j = 0; j < CAR; ++j) {          // self-state part of x
    const float w = Qw1[j * HID + t];
#pragma unroll
    for (int i = 0; i < NB; ++i) {
      const int bi = (b0 + i < B) ? (b0 + i) : (B - 1);
      a[i] = fmaf(s[(size_t)bi * SROW + j], w, a[i]);
    }
  }
#pragma unroll 8
  for (int j = 0; j < EOUT; ++j) {         // pooled-encoder part of x
    const float w = Qw1[(CAR + j) * HID + t];
#pragma unroll
    for (int i = 0; i < NB; ++i) {
      const int bi = (b0 + i < B) ? (b0 + i) : (B - 1);
      a[i] = fmaf(so[(size_t)bi * EOUT + j], w, a[i]);
    }
  }
#pragma unroll
  for (int i = 0; i < NB; ++i) hq[i][t] = fmaxf(a[i], 0.0f);
  __syncthreads();

  if (t < NB * ADIM) {
    const int bl = t / ADIM;
    const int aa = t % ADIM;
    if (b0 + bl < B) {
      float acc = Qb2[aa];
#pragma unroll 8
      for (int k = 0; k < HID; ++k)
        acc = fmaf(hq[bl][k], Qw2[k * ADIM + aa], acc);
      out[(size_t)(b0 + bl) * ADIM + aa] = acc;
    }
  }
}

extern "C" void kernel_launch(void* const* d_in, const int* in_sizes, int n_in,
                              void* d_out, int out_size, void* d_ws, size_t ws_size,
                              hipStream_t stream) {
  const float* s   = (const float*)d_in[0];
  const float* W1  = (const float*)d_in[1];
  const float* b1  = (const float*)d_in[2];
  const float* W2  = (const float*)d_in[3];
  const float* b2  = (const float*)d_in[4];
  const float* Qw1 = (const float*)d_in[5];
  const float* Qb1 = (const float*)d_in[6];
  const float* Qw2 = (const float*)d_in[7];
  const float* Qb2 = (const float*)d_in[8];
  float* out = (float*)d_out;
  const int B = in_sizes[0] / SROW;
  float* so = (float*)d_ws;   // B x 257 fp32 pooled-encoder output

  dim3 g1(B, 5);
  k1_encoder<<<g1, 64, 0, stream>>>(s, W1, b1, W2, b2, so);
  k2_qhead<<<(B + NB - 1) / NB, 256, 0, stream>>>(s, so, Qw1, Qb1, Qw2, Qb2, out, B);
}

// Round 2
// 207.558 us; speedup vs baseline: 4.4518x; 4.4518x over previous
//
#include <hip/hip_runtime.h>

#define CAR 8
#define SROW 520   // CAR + 64*CAR
#define HID 256
#define EOUT 257
#define ADIM 30
#define NB 4

typedef __attribute__((ext_vector_type(8))) short sh8;
typedef __attribute__((ext_vector_type(4))) short sh4;
typedef __attribute__((ext_vector_type(4))) float f32x4;

__device__ __forceinline__ short f2bf(float f) {
  unsigned u = __builtin_bit_cast(unsigned, f);
  u += 0x7fffu + ((u >> 16) & 1u);   // RNE to bf16
  return (short)(u >> 16);
}

// ---------------------------------------------------------------------------
// Prep: swizzle W1 -> A-fragment order (16 mtiles x 64 lanes x 8), and
// W2 -> B-fragment order (8 ksteps x 17 ntiles x 64 lanes x 8), bf16.
// Fragment convention (16x16x32 bf16): A[m=lane&15][k=quad*8+j],
// B[k=quad*8+j][n=lane&15], C/D: col=lane&15, row=quad*4+reg.
// ---------------------------------------------------------------------------
__global__ void k_prep(const float* __restrict__ W1, const float* __restrict__ W2,
                       short* __restrict__ w1f, short* __restrict__ w2f) {
  int idx = blockIdx.x * 256 + threadIdx.x;
  if (idx < 16 * 64 * 8) {           // W1^T as A: A[m=hid][k=c] = W1[c][hid]
    int mt = idx >> 9, r = idx & 511, lane = r >> 3, j = r & 7;
    int quad = lane >> 4, m = lane & 15;
    float v = (quad == 0) ? W1[j * HID + mt * 16 + m] : 0.0f;
    w1f[idx] = f2bf(v);
  }
  int i2 = idx - 16 * 64 * 8;
  if (i2 >= 0 && i2 < 8 * 17 * 64 * 8) {   // W2 as B: B[k=hid][n=col]
    int ks = i2 / (17 * 512), r = i2 % (17 * 512);
    int nt = r >> 9, r2 = r & 511, lane = r2 >> 3, j = r2 & 7;
    int quad = lane >> 4, m = lane & 15;
    int k = ks * 32 + quad * 8 + j;
    int n = nt * 16 + m;
    float v = (n < EOUT) ? W2[k * EOUT + n] : 0.0f;
    w2f[i2] = f2bf(v);
  }
}

// ---------------------------------------------------------------------------
// K1: fused encoder + pool. 1 block = 1 batch elem, 4 waves.
// Stage A: hT(256x64) = W1T(256x8) @ surrT(8x64) via MFMA, relu+b1+mask,
//          packed to LDS in stage-B A-fragment order.
// Stage B: enc-sum: each wave: M=64 agents x its 4-5 N-tiles, K=256.
// Pool: relu(c+b2) row-sum in-register + shfl_xor; -ninv*relu(b2) corrects
// for invalid agents whose h rows were zeroed.
// ---------------------------------------------------------------------------
__global__ __launch_bounds__(256, 2)
void k_enc(const float* __restrict__ s, const short* __restrict__ w1f,
           const float* __restrict__ b1, const short* __restrict__ w2f,
           const float* __restrict__ b2, float* __restrict__ so) {
  __shared__ short hlds[16384];      // 64 agents x 256 hid, frag-ordered, 32 KB
  __shared__ float validf[64];
  __shared__ float ninvs;

  const int b = blockIdx.x;
  const int tid = threadIdx.x;
  const int w = tid >> 6, lane = tid & 63;
  const int quad = lane >> 4, m = lane & 15;
  const float* srow0 = s + (size_t)b * SROW + CAR;

  // ---- phase 0: valid flags (wave 0) ----
  if (w == 0) {
    const float* sr = srow0 + lane * CAR;
    float4 f0 = ((const float4*)sr)[0], f1 = ((const float4*)sr)[1];
    bool inv = (f0.x == -1.f) | (f0.y == -1.f) | (f0.z == -1.f) | (f0.w == -1.f) |
               (f1.x == -1.f) | (f1.y == -1.f) | (f1.z == -1.f) | (f1.w == -1.f);
    validf[lane] = inv ? 0.f : 1.f;
    unsigned long long bal = __ballot(inv);
    if (lane == 0) ninvs = (float)__popcll(bal);
  }
  __syncthreads();

  // ---- phase 1: stage A ----
  {
    sh8 bs[4];
#pragma unroll
    for (int nt = 0; nt < 4; ++nt) {
      sh8 v = {0, 0, 0, 0, 0, 0, 0, 0};
      if (quad == 0) {               // B[k=j][n=agent] = surr[agent][j]
        const float* sr = srow0 + (nt * 16 + m) * CAR;
        float4 f0 = ((const float4*)sr)[0], f1 = ((const float4*)sr)[1];
        v[0] = f2bf(f0.x); v[1] = f2bf(f0.y); v[2] = f2bf(f0.z); v[3] = f2bf(f0.w);
        v[4] = f2bf(f1.x); v[5] = f2bf(f1.y); v[6] = f2bf(f1.z); v[7] = f2bf(f1.w);
      }
      bs[nt] = v;
    }
#pragma unroll
    for (int i = 0; i < 4; ++i) {
      const int mt = 4 * w + i;      // hid tile
      sh8 af = *(const sh8*)(w1f + (mt * 64 + lane) * 8);
      f32x4 c[4];
#pragma unroll
      for (int nt = 0; nt < 4; ++nt) {
        f32x4 z = {0.f, 0.f, 0.f, 0.f};
        c[nt] = __builtin_amdgcn_mfma_f32_16x16x32_bf16(af, bs[nt], z, 0, 0, 0);
      }
      const int hidb = mt * 16 + quad * 4;  // hid of reg 0
      float4 b1v = *(const float4*)(b1 + hidb);
      const int ks = hidb >> 5, qB = (hidb >> 3) & 3, js = hidb & 7;
#pragma unroll
      for (int nt = 0; nt < 4; ++nt) {
        float vv = validf[nt * 16 + m];
        sh4 pk;
        pk[0] = f2bf(fmaxf(c[nt][0] + b1v.x, 0.f) * vv);
        pk[1] = f2bf(fmaxf(c[nt][1] + b1v.y, 0.f) * vv);
        pk[2] = f2bf(fmaxf(c[nt][2] + b1v.z, 0.f) * vv);
        pk[3] = f2bf(fmaxf(c[nt][3] + b1v.w, 0.f) * vv);
        // frag-order slot: [agent-tile nt][ks][lane'=qB*16+m][j=js..js+3]
        int off = ((nt * 8 + ks) * 64 + qB * 16 + m) * 8 + js;
        *(sh4*)(hlds + off) = pk;
      }
    }
  }
  __syncthreads();

  // ---- phase 2: stage B ----
  const int NT = (w == 0) ? 5 : 4;
  int tiles[5];
#pragma unroll
  for (int i = 0; i < 4; ++i) tiles[i] = 4 * w + i;
  tiles[4] = 16;

  f32x4 acc[4][5];
#pragma unroll
  for (int mt = 0; mt < 4; ++mt)
#pragma unroll
    for (int i = 0; i < 5; ++i) {
      f32x4 z = {0.f, 0.f, 0.f, 0.f};
      acc[mt][i] = z;
    }

  for (int ks = 0; ks < 8; ++ks) {
    sh8 A[4];
#pragma unroll
    for (int mt = 0; mt < 4; ++mt)
      A[mt] = *(const sh8*)(hlds + ((mt * 8 + ks) * 64 + lane) * 8);
    sh8 Bf[5];
#pragma unroll
    for (int i = 0; i < 5; ++i)
      if (i < NT)
        Bf[i] = *(const sh8*)(w2f + ((ks * 17 + tiles[i]) * 64 + lane) * 8);
#pragma unroll
    for (int i = 0; i < 5; ++i)
      if (i < NT)
#pragma unroll
        for (int mt = 0; mt < 4; ++mt)
          acc[mt][i] = __builtin_amdgcn_mfma_f32_16x16x32_bf16(A[mt], Bf[i], acc[mt][i], 0, 0, 0);
  }

  // ---- phase 3: epilogue + pool ----
  const float ninv = ninvs;
#pragma unroll
  for (int i = 0; i < 5; ++i)
    if (i < NT) {
      const int col = tiles[i] * 16 + m;
      const float b2c = (col < EOUT) ? b2[col] : 0.f;
      float ssum = 0.f;
#pragma unroll
      for (int mt = 0; mt < 4; ++mt)
#pragma unroll
        for (int r = 0; r < 4; ++r)
          ssum += fmaxf(acc[mt][i][r] + b2c, 0.f);
      ssum += __shfl_xor(ssum, 16, 64);
      ssum += __shfl_xor(ssum, 32, 64);
      ssum -= ninv * fmaxf(b2c, 0.f);
      if (quad == 0 && col < EOUT)
        so[(size_t)b * EOUT + col] = ssum;
    }
}

// ---------------------------------------------------------------------------
// K2: Q-head (unchanged from R1 — VALU-bound, ~12-15 us).
// ---------------------------------------------------------------------------
__global__ __launch_bounds__(256)
void k2_qhead(const float* __restrict__ s, const float* __restrict__ so,
              const float* __restrict__ Qw1, const float* __restrict__ Qb1,
              const float* __restrict__ Qw2, const float* __restrict__ Qb2,
              float* __restrict__ out, int B) {
  const int t = threadIdx.x;
  const int b0 = blockIdx.x * NB;
  __shared__ float hq[NB][HID];

  float a[NB];
  const float qb = Qb1[t];
#pragma unroll
  for (int i = 0; i < NB; ++i) a[i] = qb;

#pragma unroll
  for (int j = 0; j < CAR; ++j) {
    const float w = Qw1[j * HID + t];
#pragma unroll
    for (int i = 0; i < NB; ++i) {
      const int bi = (b0 + i < B) ? (b0 + i) : (B - 1);
      a[i] = fmaf(s[(size_t)bi * SROW + j], w, a[i]);
    }
  }
#pragma unroll 8
  for (int j = 0; j < EOUT; ++j) {
    const float w = Qw1[(CAR + j) * HID + t];
#pragma unroll
    for (int i = 0; i < NB; ++i) {
      const int bi = (b0 + i < B) ? (b0 + i) : (B - 1);
      a[i] = fmaf(so[(size_t)bi * EOUT + j], w, a[i]);
    }
  }
#pragma unroll
  for (int i = 0; i < NB; ++i) hq[i][t] = fmaxf(a[i], 0.0f);
  __syncthreads();

  if (t < NB * ADIM) {
    const int bl = t / ADIM;
    const int aa = t % ADIM;
    if (b0 + bl < B) {
      float acc = Qb2[aa];
#pragma unroll 8
      for (int k = 0; k < HID; ++k)
        acc = fmaf(hq[bl][k], Qw2[k * ADIM + aa], acc);
      out[(size_t)(b0 + bl) * ADIM + aa] = acc;
    }
  }
}

extern "C" void kernel_launch(void* const* d_in, const int* in_sizes, int n_in,
                              void* d_out, int out_size, void* d_ws, size_t ws_size,
                              hipStream_t stream) {
  const float* s   = (const float*)d_in[0];
  const float* W1  = (const float*)d_in[1];
  const float* b1  = (const float*)d_in[2];
  const float* W2  = (const float*)d_in[3];
  const float* b2  = (const float*)d_in[4];
  const float* Qw1 = (const float*)d_in[5];
  const float* Qb1 = (const float*)d_in[6];
  const float* Qw2 = (const float*)d_in[7];
  const float* Qb2 = (const float*)d_in[8];
  float* out = (float*)d_out;
  const int B = in_sizes[0] / SROW;

  // ws layout: [so: B*257 f32][w1f: 8192 bf16][w2f: 69632 bf16]
  char* wsb = (char*)d_ws;
  float* so  = (float*)wsb;
  size_t so_bytes = (size_t)B * EOUT * sizeof(float);
  short* w1f = (short*)(wsb + so_bytes);
  short* w2f = (short*)(wsb + so_bytes + 16384);

  k_prep<<<(77824 + 255) / 256, 256, 0, stream>>>(W1, W2, w1f, w2f);
  k_enc<<<B, 256, 0, stream>>>(s, w1f, b1, w2f, b2, so);
  k2_qhead<<<(B + NB - 1) / NB, 256, 0, stream>>>(s, so, Qw1, Qb1, Qw2, Qb2, out, B);
}

// Round 4
// 178.414 us; speedup vs baseline: 5.1790x; 1.1634x over previous
//
#include <hip/hip_runtime.h>

#define CAR 8
#define SROW 520   // CAR + 64*CAR
#define HID 256
#define EOUT 257
#define XPAD 288   // padded Q-input row: 8 self + 257 enc + pad, 9 k-steps of 32
#define ADIM 30

typedef __attribute__((ext_vector_type(8))) short sh8;
typedef __attribute__((ext_vector_type(4))) float f32x4;

__device__ __forceinline__ short f2bf(float f) {
  unsigned u = __builtin_bit_cast(unsigned, f);
  u += 0x7fffu + ((u >> 16) & 1u);   // RNE
  return (short)(u >> 16);
}
// pack two fp32 -> packed bf16x2 (RNE), 5 VALU: 2x(shr/and-fold add) + v_perm
__device__ __forceinline__ unsigned f2bf2(float a, float b) {
  unsigned ua = __builtin_bit_cast(unsigned, a);
  ua += 0x7fffu + ((ua >> 16) & 1u);
  unsigned ub = __builtin_bit_cast(unsigned, b);
  ub += 0x7fffu + ((ub >> 16) & 1u);
  return __builtin_amdgcn_perm(ub, ua, 0x07060302);  // [a.hi16, b.hi16]
}

// ---------------------------------------------------------------------------
// Prep: swizzle all weights to bf16 MFMA fragments.
// frag convention (16x16x32): A[m=lane&15][k=quad*8+j], B[k=quad*8+j][n=lane&15],
// C/D: row(m)=quad*4+reg, col(n)=lane&15.
// w1f : W1^T as A  [16 mt][64][8]                     (8192)
// w2f : W2  as B   [8 ks][17 nt][64][8]               (69632)  stride/ks = 8704!
// w3f : Qw1 as B   [9 ks][16 nt][64][8], k=X-row idx  (73728)
// wq2f: Qw2 as B   [8 ks][2 nt][64][8]                (8192)
// ---------------------------------------------------------------------------
__global__ void k_prep(const float* __restrict__ W1, const float* __restrict__ W2,
                       const float* __restrict__ Qw1, const float* __restrict__ Qw2,
                       short* __restrict__ w1f, short* __restrict__ w2f,
                       short* __restrict__ w3f, short* __restrict__ wq2f) {
  int idx = blockIdx.x * 256 + threadIdx.x;
  if (idx < 8192) {                         // W1^T as A: A[m=hid][k=c]
    int mt = idx >> 9, r = idx & 511, lane = r >> 3, j = r & 7;
    int quad = lane >> 4, m = lane & 15;
    float v = (quad == 0) ? W1[j * HID + mt * 16 + m] : 0.0f;
    w1f[idx] = f2bf(v);
    return;
  }
  int i2 = idx - 8192;
  if (i2 < 69632) {                         // W2 as B (ks stride = 17*512 = 8704)
    int ks = i2 / 8704, r = i2 % 8704;
    int nt = r >> 9, r2 = r & 511, lane = r2 >> 3, j = r2 & 7;
    int quad = lane >> 4, m = lane & 15;
    int k = ks * 32 + quad * 8 + j, n = nt * 16 + m;
    float v = (n < EOUT) ? W2[k * EOUT + n] : 0.0f;
    w2f[i2] = f2bf(v);
    return;
  }
  int i3 = i2 - 69632;
  if (i3 < 73728) {                         // Qw1 as B (k indexes padded X row)
    int ks = i3 >> 13, r = i3 & 8191;
    int nt = r >> 9, r2 = r & 511, lane = r2 >> 3, j = r2 & 7;
    int quad = lane >> 4, m = lane & 15;
    int k = ks * 32 + quad * 8 + j, n = nt * 16 + m;
    float v = (k < 265) ? Qw1[k * HID + n] : 0.0f;
    w3f[i3] = f2bf(v);
    return;
  }
  int i4 = i3 - 73728;
  if (i4 < 8192) {                          // Qw2 as B
    int ks = i4 >> 10, r = i4 & 1023;
    int nt = r >> 9, r2 = r & 511, lane = r2 >> 3, j = r2 & 7;
    int quad = lane >> 4, m = lane & 15;
    int k = ks * 32 + quad * 8 + j, n = nt * 16 + m;
    float v = (n < ADIM) ? Qw2[k * ADIM + n] : 0.0f;
    wq2f[i4] = f2bf(v);
  }
}

// ---------------------------------------------------------------------------
// K1: fused encoder + pool. 1 block = 1 batch elem, 4 waves.
// Phase 1: wave w owns agent tile w: loads its 16 surr rows ONCE, builds the
//   B-frag + valid flags, computes hT for all 16 hid-tiles (16 MFMAs), packs
//   bf16 h into LDS in stage-B A-frag order.
// Phase 2: waves split the 17 e-tiles (5/4/4/4), K=256 fully unrolled.
// Phase 3: relu+pool epilogue -> so288 row [self(8) | enc | 0-pad].
// ---------------------------------------------------------------------------
__global__ __launch_bounds__(256, 2)
void k_enc(const float* __restrict__ s, const short* __restrict__ w1f,
           const float* __restrict__ b1, const short* __restrict__ w2f,
           const float* __restrict__ b2, float* __restrict__ so288) {
  __shared__ short hlds[16384];      // 64 agents x 256 hid bf16, frag-ordered
  __shared__ float ninvp[4];

  const int b = blockIdx.x;
  const int tid = threadIdx.x;
  const int w = tid >> 6, lane = tid & 63;
  const int q = lane >> 4, m = lane & 15;
  const float* srow0 = s + (size_t)b * SROW + CAR;

  // ---- phase 1 ----
  sh8 bs = {0, 0, 0, 0, 0, 0, 0, 0};
  bool inv = false;
  if (q == 0) {                      // quad 0: agent 16w+m
    const float* sr = srow0 + (w * 16 + m) * CAR;
    float4 f0 = ((const float4*)sr)[0], f1 = ((const float4*)sr)[1];
    inv = (f0.x == -1.f) | (f0.y == -1.f) | (f0.z == -1.f) | (f0.w == -1.f) |
          (f1.x == -1.f) | (f1.y == -1.f) | (f1.z == -1.f) | (f1.w == -1.f);
    unsigned u0 = f2bf2(f0.x, f0.y), u1 = f2bf2(f0.z, f0.w);
    unsigned u2 = f2bf2(f1.x, f1.y), u3 = f2bf2(f1.z, f1.w);
    int4 t = {(int)u0, (int)u1, (int)u2, (int)u3};
    bs = __builtin_bit_cast(sh8, t);
  }
  const float vflag = inv ? 0.f : 1.f;
  const float vv = __shfl(vflag, m, 64);        // flag of agent 16w + (lane&15)
  unsigned long long bal = __ballot(inv);       // only quad0 lanes can be set
  if (lane == 0) ninvp[w] = (float)__popcll(bal);

#pragma unroll
  for (int mt = 0; mt < 16; ++mt) {
    sh8 af = *(const sh8*)(w1f + (mt * 64 + lane) * 8);
    f32x4 z = {0.f, 0.f, 0.f, 0.f};
    f32x4 c = __builtin_amdgcn_mfma_f32_16x16x32_bf16(af, bs, z, 0, 0, 0);
    const int hidb = mt * 16 + q * 4;
    float4 b1v = *(const float4*)(b1 + hidb);
    const int ks = hidb >> 5, qB = (hidb >> 3) & 3, js = hidb & 7;
    unsigned p0 = f2bf2(fmaxf(c[0] + b1v.x, 0.f) * vv, fmaxf(c[1] + b1v.y, 0.f) * vv);
    unsigned p1 = f2bf2(fmaxf(c[2] + b1v.z, 0.f) * vv, fmaxf(c[3] + b1v.w, 0.f) * vv);
    uint2 pk = {p0, p1};
    *(uint2*)(hlds + ((w * 8 + ks) * 64 + qB * 16 + m) * 8 + js) = pk;
  }
  __syncthreads();

  // ---- phase 2 ----
  const int NT = (w == 0) ? 5 : 4;
  int tiles[5];
#pragma unroll
  for (int i = 0; i < 4; ++i) tiles[i] = 4 * w + i;
  tiles[4] = 16;

  f32x4 acc[4][5];
#pragma unroll
  for (int mt = 0; mt < 4; ++mt)
#pragma unroll
    for (int i = 0; i < 5; ++i) {
      f32x4 z = {0.f, 0.f, 0.f, 0.f};
      acc[mt][i] = z;
    }

#pragma unroll
  for (int ks = 0; ks < 8; ++ks) {
    sh8 A[4];
#pragma unroll
    for (int mt = 0; mt < 4; ++mt)
      A[mt] = *(const sh8*)(hlds + ((mt * 8 + ks) * 64 + lane) * 8);
    sh8 Bf[5];
#pragma unroll
    for (int i = 0; i < 5; ++i)
      if (i < NT)
        Bf[i] = *(const sh8*)(w2f + ((ks * 17 + tiles[i]) * 64 + lane) * 8);
#pragma unroll
    for (int i = 0; i < 5; ++i)
      if (i < NT)
#pragma unroll
        for (int mt = 0; mt < 4; ++mt)
          acc[mt][i] = __builtin_amdgcn_mfma_f32_16x16x32_bf16(A[mt], Bf[i], acc[mt][i], 0, 0, 0);
  }

  // ---- phase 3 ----
  const float ninv = ninvp[0] + ninvp[1] + ninvp[2] + ninvp[3];
#pragma unroll
  for (int i = 0; i < 5; ++i)
    if (i < NT) {
      const int col = tiles[i] * 16 + m;           // 0..271
      const float b2c = (col < EOUT) ? b2[col] : 0.f;
      float ssum = 0.f;
#pragma unroll
      for (int mt = 0; mt < 4; ++mt)
#pragma unroll
        for (int r = 0; r < 4; ++r)
          ssum += fmaxf(acc[mt][i][r] + b2c, 0.f);
      ssum += __shfl_xor(ssum, 16, 64);
      ssum += __shfl_xor(ssum, 32, 64);
      ssum -= ninv * fmaxf(b2c, 0.f);              // pad cols: b2c=0 -> writes 0
      if (q == 0)
        so288[(size_t)b * XPAD + CAR + col] = ssum;
    }
  if (w == 1 && lane < CAR)                        // fuse self-state into X row
    so288[(size_t)b * XPAD + lane] = s[(size_t)b * SROW + lane];
  if (w == 2 && lane < 8)                          // zero the tail pad 280..287
    so288[(size_t)b * XPAD + 280 + lane] = 0.f;
}

// ---------------------------------------------------------------------------
// K2: Q-head, MFMA. 1 block = 1 wave = 16 batch rows.
// L1: X(16x288) @ Qw1 -> H(16x256): A-frags straight from so288 (2 float4 +
//     4 packs), B-frags prep-swizzled (L2-resident). relu -> H fp32 in LDS
//     (row stride 260: 2-way banks = free, 16B aligned).
// L2: H(16x256) @ Qw2(256x32pad) -> out, C-layout scatter store.
// ---------------------------------------------------------------------------
__global__ __launch_bounds__(64, 2)
void k_q(const float* __restrict__ so288, const short* __restrict__ w3f,
         const float* __restrict__ Qb1, const short* __restrict__ wq2f,
         const float* __restrict__ Qb2, float* __restrict__ out, int B) {
  __shared__ float H[16 * 260];
  const int lane = threadIdx.x;
  const int q = lane >> 4, m = lane & 15;
  const int b0 = blockIdx.x * 16;
  int row = b0 + m; if (row >= B) row = B - 1;
  const float* xr = so288 + (size_t)row * XPAD;

  f32x4 acc1[16];
#pragma unroll
  for (int nt = 0; nt < 16; ++nt) {
    f32x4 z = {0.f, 0.f, 0.f, 0.f};
    acc1[nt] = z;
  }

#pragma unroll
  for (int ks = 0; ks < 9; ++ks) {
    const float* xp = xr + ks * 32 + q * 8;
    float4 xa = ((const float4*)xp)[0], xb = ((const float4*)xp)[1];
    unsigned u0 = f2bf2(xa.x, xa.y), u1 = f2bf2(xa.z, xa.w);
    unsigned u2 = f2bf2(xb.x, xb.y), u3 = f2bf2(xb.z, xb.w);
    int4 t = {(int)u0, (int)u1, (int)u2, (int)u3};
    sh8 A = __builtin_bit_cast(sh8, t);
#pragma unroll
    for (int nt = 0; nt < 16; ++nt) {
      sh8 Bf = *(const sh8*)(w3f + ((ks * 16 + nt) * 64 + lane) * 8);
      acc1[nt] = __builtin_amdgcn_mfma_f32_16x16x32_bf16(A, Bf, acc1[nt], 0, 0, 0);
    }
  }
  // epilogue 1: +Qb1, relu -> H[batch][hid] fp32 (stride 260)
#pragma unroll
  for (int nt = 0; nt < 16; ++nt) {
    const float bq = Qb1[nt * 16 + m];
#pragma unroll
    for (int r = 0; r < 4; ++r)
      H[(q * 4 + r) * 260 + nt * 16 + m] = fmaxf(acc1[nt][r] + bq, 0.f);
  }
  __syncthreads();   // single-wave block: proper compiler+HW fence for LDS RAW

  f32x4 acc2[2];
#pragma unroll
  for (int nt = 0; nt < 2; ++nt) {
    f32x4 z = {0.f, 0.f, 0.f, 0.f};
    acc2[nt] = z;
  }
#pragma unroll
  for (int ks = 0; ks < 8; ++ks) {
    const float* hp = H + m * 260 + ks * 32 + q * 8;
    float4 ha = ((const float4*)hp)[0], hb = ((const float4*)hp)[1];
    unsigned u0 = f2bf2(ha.x, ha.y), u1 = f2bf2(ha.z, ha.w);
    unsigned u2 = f2bf2(hb.x, hb.y), u3 = f2bf2(hb.z, hb.w);
    int4 t = {(int)u0, (int)u1, (int)u2, (int)u3};
    sh8 A2 = __builtin_bit_cast(sh8, t);
#pragma unroll
    for (int nt = 0; nt < 2; ++nt) {
      sh8 Bf = *(const sh8*)(wq2f + ((ks * 2 + nt) * 64 + lane) * 8);
      acc2[nt] = __builtin_amdgcn_mfma_f32_16x16x32_bf16(A2, Bf, acc2[nt], 0, 0, 0);
    }
  }
#pragma unroll
  for (int nt = 0; nt < 2; ++nt) {
    const int act = nt * 16 + m;
    if (act < ADIM) {
      const float bq = Qb2[act];
#pragma unroll
      for (int r = 0; r < 4; ++r) {
        const int br = b0 + q * 4 + r;
        if (br < B) out[(size_t)br * ADIM + act] = acc2[nt][r] + bq;
      }
    }
  }
}

extern "C" void kernel_launch(void* const* d_in, const int* in_sizes, int n_in,
                              void* d_out, int out_size, void* d_ws, size_t ws_size,
                              hipStream_t stream) {
  const float* s   = (const float*)d_in[0];
  const float* W1  = (const float*)d_in[1];
  const float* b1  = (const float*)d_in[2];
  const float* W2  = (const float*)d_in[3];
  const float* b2  = (const float*)d_in[4];
  const float* Qw1 = (const float*)d_in[5];
  const float* Qb1 = (const float*)d_in[6];
  const float* Qw2 = (const float*)d_in[7];
  const float* Qb2 = (const float*)d_in[8];
  float* out = (float*)d_out;
  const int B = in_sizes[0] / SROW;

  // ws: [so288: B*288 f32][w1f 8192][w2f 69632][w3f 73728][wq2f 8192] bf16
  char* wsb = (char*)d_ws;
  float* so288 = (float*)wsb;
  size_t off = (size_t)B * XPAD * sizeof(float);
  short* w1f  = (short*)(wsb + off);            off += 8192 * 2;
  short* w2f  = (short*)(wsb + off);            off += 69632 * 2;
  short* w3f  = (short*)(wsb + off);            off += 73728 * 2;
  short* wq2f = (short*)(wsb + off);

  const int prep_elems = 8192 + 69632 + 73728 + 8192;
  k_prep<<<(prep_elems + 255) / 256, 256, 0, stream>>>(W1, W2, Qw1, Qw2,
                                                       w1f, w2f, w3f, wq2f);
  k_enc<<<B, 256, 0, stream>>>(s, w1f, b1, w2f, b2, so288);
  k_q<<<(B + 15) / 16, 64, 0, stream>>>(so288, w3f, Qb1, wq2f, Qb2, out, B);
}

// Round 5
// 168.732 us; speedup vs baseline: 5.4762x; 1.0574x over previous
//
#include <hip/hip_runtime.h>

#define CAR 8
#define SROW 520   // CAR + 64*CAR
#define HID 256
#define EOUT 257
#define XPAD 288   // padded Q-input row: 8 self + 257 enc + pad, 9 k-steps of 32
#define ADIM 30

typedef __attribute__((ext_vector_type(8))) short sh8;
typedef __attribute__((ext_vector_type(4))) float f32x4;

__device__ __forceinline__ short f2bf(float f) {
  unsigned u = __builtin_bit_cast(unsigned, f);
  u += 0x7fffu + ((u >> 16) & 1u);   // RNE
  return (short)(u >> 16);
}
// pack two fp32 -> packed bf16x2 (RNE)
__device__ __forceinline__ unsigned f2bf2(float a, float b) {
  unsigned ua = __builtin_bit_cast(unsigned, a);
  ua += 0x7fffu + ((ua >> 16) & 1u);
  unsigned ub = __builtin_bit_cast(unsigned, b);
  ub += 0x7fffu + ((ub >> 16) & 1u);
  return __builtin_amdgcn_perm(ub, ua, 0x07060302);  // [a.hi16, b.hi16]
}

// ---------------------------------------------------------------------------
// Prep: swizzle all weights to bf16 MFMA fragments.
// frag convention (16x16x32): A[m=lane&15][k=quad*8+j], B[k=quad*8+j][n=lane&15],
// C/D: row(m)=quad*4+reg, col(n)=lane&15.
// w1f : W1^T as A  [16 mt][64][8]                     (8192)
// w2f : W2  as B   [8 ks][17 nt][64][8]               (69632)  stride/ks = 8704!
// w3f : Qw1 as B   [9 ks][16 nt][64][8], k=X-row idx  (73728)
// wq2f: Qw2 as B   [8 ks][2 nt][64][8]                (8192)
// ---------------------------------------------------------------------------
__global__ void k_prep(const float* __restrict__ W1, const float* __restrict__ W2,
                       const float* __restrict__ Qw1, const float* __restrict__ Qw2,
                       short* __restrict__ w1f, short* __restrict__ w2f,
                       short* __restrict__ w3f, short* __restrict__ wq2f) {
  int idx = blockIdx.x * 256 + threadIdx.x;
  if (idx < 8192) {                         // W1^T as A: A[m=hid][k=c]
    int mt = idx >> 9, r = idx & 511, lane = r >> 3, j = r & 7;
    int quad = lane >> 4, m = lane & 15;
    float v = (quad == 0) ? W1[j * HID + mt * 16 + m] : 0.0f;
    w1f[idx] = f2bf(v);
    return;
  }
  int i2 = idx - 8192;
  if (i2 < 69632) {                         // W2 as B (ks stride = 17*512 = 8704)
    int ks = i2 / 8704, r = i2 % 8704;
    int nt = r >> 9, r2 = r & 511, lane = r2 >> 3, j = r2 & 7;
    int quad = lane >> 4, m = lane & 15;
    int k = ks * 32 + quad * 8 + j, n = nt * 16 + m;
    float v = (n < EOUT) ? W2[k * EOUT + n] : 0.0f;
    w2f[i2] = f2bf(v);
    return;
  }
  int i3 = i2 - 69632;
  if (i3 < 73728) {                         // Qw1 as B (k indexes padded X row)
    int ks = i3 >> 13, r = i3 & 8191;
    int nt = r >> 9, r2 = r & 511, lane = r2 >> 3, j = r2 & 7;
    int quad = lane >> 4, m = lane & 15;
    int k = ks * 32 + quad * 8 + j, n = nt * 16 + m;
    float v = (k < 265) ? Qw1[k * HID + n] : 0.0f;
    w3f[i3] = f2bf(v);
    return;
  }
  int i4 = i3 - 73728;
  if (i4 < 8192) {                          // Qw2 as B
    int ks = i4 >> 10, r = i4 & 1023;
    int nt = r >> 9, r2 = r & 511, lane = r2 >> 3, j = r2 & 7;
    int quad = lane >> 4, m = lane & 15;
    int k = ks * 32 + quad * 8 + j, n = nt * 16 + m;
    float v = (n < ADIM) ? Qw2[k * ADIM + n] : 0.0f;
    wq2f[i4] = f2bf(v);
  }
}

// ---------------------------------------------------------------------------
// K1: fused encoder + pool, NB=2 batch elems per block, 4 waves.
// Phase 1: wave w -> be=w>>1, half=w&1: lanes 0..31 load agent rows
//   32*half+lane; B-frags for agent-tiles {2h,2h+1} built via shfl; 16 mt
//   MFMAs x2 tiles; relu+b1+mask packed bf16 -> hlds[be] in A-frag order.
// Phase 2: uniform 5 N-tiles/wave (w0: {0..3,16}; w1-3: dup of own tile 0),
//   explicit Bf double-buffer; be inner loop reuses Bf registers (halves L2
//   w2f traffic vs R4).
// Phase 3: relu+pool epilogue -> so288 rows.
// ---------------------------------------------------------------------------
__global__ __launch_bounds__(256, 2)
void k_enc(const float* __restrict__ s, const short* __restrict__ w1f,
           const float* __restrict__ b1, const short* __restrict__ w2f,
           const float* __restrict__ b2, float* __restrict__ so288) {
  __shared__ __align__(16) short hlds[2][16384];  // 2 x (64 agents x 256 hid) bf16
  __shared__ float ninvp[4];

  const int tid = threadIdx.x;
  const int w = tid >> 6, lane = tid & 63;
  const int q = lane >> 4, m = lane & 15;
  const int be = w >> 1, half = w & 1;
  const size_t b0 = 2 * (size_t)blockIdx.x;
  const int bg = (int)b0 + be;

  // ---- phase 1 ----
  const float* srow0 = s + (size_t)bg * SROW + CAR;
  int4 pk = {0, 0, 0, 0};
  bool inv = false;
  if (lane < 32) {                   // agent (local in be) = 32*half + lane
    const float* sr = srow0 + (half * 32 + lane) * CAR;
    float4 f0 = ((const float4*)sr)[0], f1 = ((const float4*)sr)[1];
    inv = (f0.x == -1.f) | (f0.y == -1.f) | (f0.z == -1.f) | (f0.w == -1.f) |
          (f1.x == -1.f) | (f1.y == -1.f) | (f1.z == -1.f) | (f1.w == -1.f);
    pk.x = (int)f2bf2(f0.x, f0.y); pk.y = (int)f2bf2(f0.z, f0.w);
    pk.z = (int)f2bf2(f1.x, f1.y); pk.w = (int)f2bf2(f1.z, f1.w);
  }
  const float vflag = inv ? 0.f : 1.f;
  unsigned long long bal = __ballot(inv);
  if (lane == 0) ninvp[w] = (float)__popcll(bal);

  int4 p0, p1;
  p0.x = __shfl(pk.x, m, 64);      p0.y = __shfl(pk.y, m, 64);
  p0.z = __shfl(pk.z, m, 64);      p0.w = __shfl(pk.w, m, 64);
  p1.x = __shfl(pk.x, 16 + m, 64); p1.y = __shfl(pk.y, 16 + m, 64);
  p1.z = __shfl(pk.z, 16 + m, 64); p1.w = __shfl(pk.w, 16 + m, 64);
  const float vv0 = __shfl(vflag, m, 64);
  const float vv1 = __shfl(vflag, 16 + m, 64);
  if (q != 0) { p0.x = p0.y = p0.z = p0.w = 0; p1.x = p1.y = p1.z = p1.w = 0; }
  sh8 bs0 = __builtin_bit_cast(sh8, p0);
  sh8 bs1 = __builtin_bit_cast(sh8, p1);

  const int T0 = half * 2, T1 = half * 2 + 1;
#pragma unroll
  for (int mt = 0; mt < 16; ++mt) {
    sh8 af = *(const sh8*)(w1f + (mt * 64 + lane) * 8);
    f32x4 z = {0.f, 0.f, 0.f, 0.f};
    f32x4 c0 = __builtin_amdgcn_mfma_f32_16x16x32_bf16(af, bs0, z, 0, 0, 0);
    f32x4 c1 = __builtin_amdgcn_mfma_f32_16x16x32_bf16(af, bs1, z, 0, 0, 0);
    const int hidb = mt * 16 + q * 4;
    float4 b1v = *(const float4*)(b1 + hidb);
    const int ks = hidb >> 5, qB = (hidb >> 3) & 3, js = hidb & 7;
    uint2 k0, k1;
    k0.x = f2bf2(fmaxf(c0[0] + b1v.x, 0.f) * vv0, fmaxf(c0[1] + b1v.y, 0.f) * vv0);
    k0.y = f2bf2(fmaxf(c0[2] + b1v.z, 0.f) * vv0, fmaxf(c0[3] + b1v.w, 0.f) * vv0);
    k1.x = f2bf2(fmaxf(c1[0] + b1v.x, 0.f) * vv1, fmaxf(c1[1] + b1v.y, 0.f) * vv1);
    k1.y = f2bf2(fmaxf(c1[2] + b1v.z, 0.f) * vv1, fmaxf(c1[3] + b1v.w, 0.f) * vv1);
    *(uint2*)(&hlds[be][((T0 * 8 + ks) * 64 + qB * 16 + m) * 8 + js]) = k0;
    *(uint2*)(&hlds[be][((T1 * 8 + ks) * 64 + qB * 16 + m) * 8 + js]) = k1;
  }
  __syncthreads();

  // ---- phase 2 ----
  int tiles[5];
#pragma unroll
  for (int i = 0; i < 4; ++i) tiles[i] = 4 * w + i;
  tiles[4] = (w == 0) ? 16 : 4 * w;          // dup for w!=0 (uniform code)

  f32x4 acc[4][5][2];
#pragma unroll
  for (int mt = 0; mt < 4; ++mt)
#pragma unroll
    for (int i = 0; i < 5; ++i)
#pragma unroll
      for (int e = 0; e < 2; ++e) {
        f32x4 z = {0.f, 0.f, 0.f, 0.f};
        acc[mt][i][e] = z;
      }

  sh8 Bf[5];
#pragma unroll
  for (int i = 0; i < 5; ++i)
    Bf[i] = *(const sh8*)(w2f + ((0 * 17 + tiles[i]) * 64 + lane) * 8);

#pragma unroll
  for (int ks = 0; ks < 8; ++ks) {
    sh8 Bn[5];
    if (ks < 7) {
#pragma unroll
      for (int i = 0; i < 5; ++i)
        Bn[i] = *(const sh8*)(w2f + (((ks + 1) * 17 + tiles[i]) * 64 + lane) * 8);
    }
#pragma unroll
    for (int e = 0; e < 2; ++e) {
      sh8 A[4];
#pragma unroll
      for (int mt = 0; mt < 4; ++mt)
        A[mt] = *(const sh8*)(&hlds[e][((mt * 8 + ks) * 64 + lane) * 8]);
#pragma unroll
      for (int i = 0; i < 5; ++i)
#pragma unroll
        for (int mt = 0; mt < 4; ++mt)
          acc[mt][i][e] = __builtin_amdgcn_mfma_f32_16x16x32_bf16(A[mt], Bf[i], acc[mt][i][e], 0, 0, 0);
    }
    if (ks < 7) {
#pragma unroll
      for (int i = 0; i < 5; ++i) Bf[i] = Bn[i];
    }
  }

  // ---- phase 3 ----
  const float ninv[2] = {ninvp[0] + ninvp[1], ninvp[2] + ninvp[3]};
#pragma unroll
  for (int i = 0; i < 5; ++i) {
    if (i == 4 && w != 0) continue;          // dup tile: no output
    const int col = tiles[i] * 16 + m;       // 0..271
    const float b2c = (col < EOUT) ? b2[col] : 0.f;
    const float rb2 = fmaxf(b2c, 0.f);
#pragma unroll
    for (int e = 0; e < 2; ++e) {
      float ssum = 0.f;
#pragma unroll
      for (int mt = 0; mt < 4; ++mt)
#pragma unroll
        for (int r = 0; r < 4; ++r)
          ssum += fmaxf(acc[mt][i][e][r] + b2c, 0.f);
      ssum += __shfl_xor(ssum, 16, 64);
      ssum += __shfl_xor(ssum, 32, 64);
      ssum -= ninv[e] * rb2;                 // pad cols: b2c=0 -> writes 0
      if (q == 0)
        so288[(b0 + e) * XPAD + CAR + col] = ssum;
    }
  }
  if (w == 1 || w == 2) {                    // self-state + tail pad per be
    const size_t rr = b0 + (w - 1);
    if (lane < CAR)       so288[rr * XPAD + lane] = s[rr * SROW + lane];
    else if (lane < 16)   so288[rr * XPAD + 280 + (lane - 8)] = 0.f;
  }
}

// ---------------------------------------------------------------------------
// K2: Q-head, MFMA. 4 waves, 32 batch rows per block (256 blocks at B=8192).
// Stage X(32x288) -> LDS in A-frag order (w3f reads amortized 32x).
// GEMM1: wave w owns hid-tiles 4w..4w+3; H fp32 -> LDS (stride 260).
// GEMM2: wave w -> (mt=w>>1, nt=w&1), K=256; C-layout store.
// ---------------------------------------------------------------------------
__global__ __launch_bounds__(256, 2)
void k_q(const float* __restrict__ so288, const short* __restrict__ w3f,
         const float* __restrict__ Qb1, const short* __restrict__ wq2f,
         const float* __restrict__ Qb2, float* __restrict__ out, int B) {
  __shared__ __align__(16) short xf[2 * 9 * 64 * 8];  // 36 KB, [mt][ks][lane][j]
  __shared__ __align__(16) float H[32 * 260];          // 33.3 KB
  const int tid = threadIdx.x;
  const int w = tid >> 6, lane = tid & 63;
  const int q = lane >> 4, m = lane & 15;
  const int b0 = blockIdx.x * 32;

  // ---- stage X ----
#pragma unroll
  for (int it = 0; it < 5; ++it) {
    int sidx = tid + it * 256;               // = (mt*9+ks)*64 + l
    if (sidx < 1152) {
      int mt = sidx / 576, rem = sidx % 576;
      int ks = rem >> 6, l = rem & 63;
      int lq = l >> 4, lm = l & 15;
      int row = b0 + mt * 16 + lm; if (row >= B) row = B - 1;
      const float* xp = so288 + (size_t)row * XPAD + ks * 32 + lq * 8;
      float4 xa = ((const float4*)xp)[0], xb = ((const float4*)xp)[1];
      int4 t = {(int)f2bf2(xa.x, xa.y), (int)f2bf2(xa.z, xa.w),
                (int)f2bf2(xb.x, xb.y), (int)f2bf2(xb.z, xb.w)};
      *(int4*)(xf + sidx * 8) = t;
    }
  }
  __syncthreads();

  // ---- GEMM1: X(32x288) @ Qw1 -> H ----
  f32x4 acc1[2][4];
#pragma unroll
  for (int mt = 0; mt < 2; ++mt)
#pragma unroll
    for (int i = 0; i < 4; ++i) {
      f32x4 z = {0.f, 0.f, 0.f, 0.f};
      acc1[mt][i] = z;
    }
#pragma unroll
  for (int ks = 0; ks < 9; ++ks) {
    sh8 A0 = *(const sh8*)(xf + ((0 * 9 + ks) * 64 + lane) * 8);
    sh8 A1 = *(const sh8*)(xf + ((1 * 9 + ks) * 64 + lane) * 8);
#pragma unroll
    for (int i = 0; i < 4; ++i) {
      sh8 Bf = *(const sh8*)(w3f + ((ks * 16 + 4 * w + i) * 64 + lane) * 8);
      acc1[0][i] = __builtin_amdgcn_mfma_f32_16x16x32_bf16(A0, Bf, acc1[0][i], 0, 0, 0);
      acc1[1][i] = __builtin_amdgcn_mfma_f32_16x16x32_bf16(A1, Bf, acc1[1][i], 0, 0, 0);
    }
  }
#pragma unroll
  for (int i = 0; i < 4; ++i) {
    const int hcol = (4 * w + i) * 16 + m;
    const float bq = Qb1[hcol];
#pragma unroll
    for (int mt = 0; mt < 2; ++mt)
#pragma unroll
      for (int r = 0; r < 4; ++r)
        H[(mt * 16 + q * 4 + r) * 260 + hcol] = fmaxf(acc1[mt][i][r] + bq, 0.f);
  }
  __syncthreads();

  // ---- GEMM2: H(32x256) @ Qw2 -> out ----
  const int mt2 = w >> 1, nt2 = w & 1;
  f32x4 acc2 = {0.f, 0.f, 0.f, 0.f};
#pragma unroll
  for (int ks = 0; ks < 8; ++ks) {
    const float* hp = H + (mt2 * 16 + m) * 260 + ks * 32 + q * 8;
    float4 ha = ((const float4*)hp)[0], hb = ((const float4*)hp)[1];
    int4 t = {(int)f2bf2(ha.x, ha.y), (int)f2bf2(ha.z, ha.w),
              (int)f2bf2(hb.x, hb.y), (int)f2bf2(hb.z, hb.w)};
    sh8 A2 = __builtin_bit_cast(sh8, t);
    sh8 Bf = *(const sh8*)(wq2f + ((ks * 2 + nt2) * 64 + lane) * 8);
    acc2 = __builtin_amdgcn_mfma_f32_16x16x32_bf16(A2, Bf, acc2, 0, 0, 0);
  }
  const int act = nt2 * 16 + m;
  if (act < ADIM) {
    const float bq = Qb2[act];
#pragma unroll
    for (int r = 0; r < 4; ++r) {
      const int row = b0 + mt2 * 16 + q * 4 + r;
      if (row < B) out[(size_t)row * ADIM + act] = acc2[r] + bq;
    }
  }
}

extern "C" void kernel_launch(void* const* d_in, const int* in_sizes, int n_in,
                              void* d_out, int out_size, void* d_ws, size_t ws_size,
                              hipStream_t stream) {
  const float* s   = (const float*)d_in[0];
  const float* W1  = (const float*)d_in[1];
  const float* b1  = (const float*)d_in[2];
  const float* W2  = (const float*)d_in[3];
  const float* b2  = (const float*)d_in[4];
  const float* Qw1 = (const float*)d_in[5];
  const float* Qb1 = (const float*)d_in[6];
  const float* Qw2 = (const float*)d_in[7];
  const float* Qb2 = (const float*)d_in[8];
  float* out = (float*)d_out;
  const int B = in_sizes[0] / SROW;

  // ws: [so288: B*288 f32][w1f 8192][w2f 69632][w3f 73728][wq2f 8192] bf16
  char* wsb = (char*)d_ws;
  float* so288 = (float*)wsb;
  size_t off = (size_t)B * XPAD * sizeof(float);
  short* w1f  = (short*)(wsb + off);            off += 8192 * 2;
  short* w2f  = (short*)(wsb + off);            off += 69632 * 2;
  short* w3f  = (short*)(wsb + off);            off += 73728 * 2;
  short* wq2f = (short*)(wsb + off);

  const int prep_elems = 8192 + 69632 + 73728 + 8192;
  k_prep<<<(prep_elems + 255) / 256, 256, 0, stream>>>(W1, W2, Qw1, Qw2,
                                                       w1f, w2f, w3f, wq2f);
  k_enc<<<(B + 1) / 2, 256, 0, stream>>>(s, w1f, b1, w2f, b2, so288);
  k_q<<<(B + 31) / 32, 256, 0, stream>>>(so288, w3f, Qb1, wq2f, Qb2, out, B);
}